// Round 9
// baseline (491.262 us; speedup 1.0000x reference)
//
#include <hip/hip_runtime.h>

// ---------------------------------------------------------------------------
// TapeHead R9: windowed chunk proj -> QKV -> MHA -> out proj -> LN.
// B=4 S=2048 D=1024 C=2 H=16, M=8192.
// R9: (a) attn reverted to R6 (shfl-based PV, K=16 — R8's K=8 PV cost +15us
// of matrix-pipe); (b) gemm_bt templated on N-tile: NT=64 for N=1024 GEMMs
// (512->1024 blocks; 2->4 blocks/CU; fixes grid starvation), NT=128 for QKV.
// ---------------------------------------------------------------------------

typedef __bf16 bf16x8 __attribute__((ext_vector_type(8)));
typedef float f32x4 __attribute__((ext_vector_type(4)));
typedef float f32x16 __attribute__((ext_vector_type(16)));

#if __has_builtin(__builtin_amdgcn_exp2f)
#define EXP2(x) __builtin_amdgcn_exp2f(x)
#else
#define EXP2(x) exp2f(x)
#endif

__device__ __forceinline__ unsigned short f2bf(float x) {
  unsigned u = __float_as_uint(x);
  u += 0x7fffu + ((u >> 16) & 1u);
  return (unsigned short)(u >> 16);
}

__device__ __forceinline__ float bf2f(unsigned short x) {
  return __uint_as_float(((unsigned)x) << 16);
}

// async global->LDS, 16B per lane; LDS dest = wave-uniform base + lane*16
__device__ __forceinline__ void glds16(const ushort* g, ushort* l) {
  __builtin_amdgcn_global_load_lds(
      (const __attribute__((address_space(1))) unsigned int*)g,
      (__attribute__((address_space(3))) unsigned int*)l, 16, 0, 0);
}

// ---------------------------------------------------------------------------
// Build windowed A: A_win[m][k], k<1024 -> emb[m][k]; k>=1024 -> emb[m+1][k-1024]
// (zeros when s==S-1).
// ---------------------------------------------------------------------------
__global__ __launch_bounds__(256) void build_awin(const float* __restrict__ emb,
                                                  ushort* __restrict__ aw) {
  const int i = blockIdx.x * 256 + threadIdx.x;
  const int e = i * 4;
  const int m = e >> 11;
  const int k = e & 2047;
  float4 v;
  if (k < 1024) {
    v = *(const float4*)(emb + (size_t)m * 1024 + k);
  } else {
    const int s = m & 2047;
    if (s == 2047) v = make_float4(0.f, 0.f, 0.f, 0.f);
    else           v = *(const float4*)(emb + (size_t)(m + 1) * 1024 + (k - 1024));
  }
  ushort4 o;
  o.x = f2bf(v.x); o.y = f2bf(v.y); o.z = f2bf(v.z); o.w = f2bf(v.w);
  *(ushort4*)(aw + (size_t)e) = o;
}

__global__ __launch_bounds__(256) void cvt_bf16(const float* __restrict__ in,
                                                ushort* __restrict__ out, int n4) {
  const int i = blockIdx.x * 256 + threadIdx.x;
  if (i >= n4) return;
  float4 v = ((const float4*)in)[i];
  ushort4 o;
  o.x = f2bf(v.x); o.y = f2bf(v.y); o.z = f2bf(v.z); o.w = f2bf(v.w);
  ((ushort4*)out)[i] = o;
}

// ---------------------------------------------------------------------------
// gemm_bt<NT>: C[m][n] = sum_k A[m][k]*W[n][k] + bias[n]; 128xNT tile, 4 waves
// (2x2), 16x16x32 MFMA, BK=64, global_load_lds into plane layout
// [kslot][row] (slot = 16B).  NT=128: 32KB LDS; NT=64: 24KB LDS (6 blk/CU).
// Grid: x = mb (M/128), y = nb (N/NT)  -- XCD = mb%8 keeps A-tile L2-local.
// Modes: 0: outb bf16; 1: outb bf16, cols n<1024 pre-scaled by log2(e)/8 (Q);
//        2: outf = acc + bias + bf2f(residb).
// ---------------------------------------------------------------------------
template <int NT>
__global__ __launch_bounds__(256) void gemm_bt(
    const ushort* __restrict__ A, const ushort* __restrict__ W,
    const float* __restrict__ bias, int M, int N, int K, int mode,
    float* __restrict__ outf, ushort* __restrict__ outb,
    const ushort* __restrict__ residb) {
  constexpr int NTC = NT / 32;      // per-wave 16-col tiles (128->4, 64->2)
  constexpr int BC  = NT / 32;      // B staging calls per wave
  __shared__ __align__(16) ushort sA[8192];      // 8 kslots * 128 rows * 8
  __shared__ __align__(16) ushort sB[NT * 64];   // 8 kslots * NT rows * 8
  const int t = threadIdx.x, wave = t >> 6, lane = t & 63;
  const int c16 = lane & 15, quad = lane >> 4;
  const int wm = wave >> 1, wn = wave & 1;
  const int m0 = blockIdx.x * 128, n0 = blockIdx.y * NT;
  f32x4 acc[4][NTC] = {};
  const ushort* gA[4];
  const ushort* gB[BC];
  ushort* lA[4];
  ushort* lB[BC];
#pragma unroll
  for (int c = 0; c < 4; ++c) {
    const int j = wave * 4 + c;
    const int ks = j >> 1, row = (j & 1) * 64 + lane;
    gA[c] = A + (size_t)(m0 + row) * K + ks * 8;
    lA[c] = sA + j * 512;
  }
#pragma unroll
  for (int c = 0; c < BC; ++c) {
    const int j = wave * BC + c;
    int ksb, rowb;
    if (NT == 128) { ksb = j >> 1; rowb = (j & 1) * 64 + lane; }
    else           { ksb = j;      rowb = lane; }
    gB[c] = W + (size_t)(n0 + rowb) * K + ksb * 8;
    lB[c] = sB + j * 512;
  }
  for (int k0 = 0; k0 < K; k0 += 64) {
    __syncthreads();
#pragma unroll
    for (int c = 0; c < 4; ++c) glds16(gA[c] + k0, lA[c]);
#pragma unroll
    for (int c = 0; c < BC; ++c) glds16(gB[c] + k0, lB[c]);
    __syncthreads();
#pragma unroll
    for (int kc = 0; kc < 2; ++kc) {
      bf16x8 af[4], bfr[NTC];
#pragma unroll
      for (int i = 0; i < 4; ++i)
        af[i] = *(const bf16x8*)(sA + ((kc * 4 + quad) * 128 + wm * 64 + i * 16 + c16) * 8);
#pragma unroll
      for (int i = 0; i < NTC; ++i)
        bfr[i] = *(const bf16x8*)(sB + ((kc * 4 + quad) * NT + wn * (NT / 2) + i * 16 + c16) * 8);
#pragma unroll
      for (int mt = 0; mt < 4; ++mt)
#pragma unroll
        for (int nt = 0; nt < NTC; ++nt)
          acc[mt][nt] = __builtin_amdgcn_mfma_f32_16x16x32_bf16(af[mt], bfr[nt],
                                                                acc[mt][nt], 0, 0, 0);
    }
  }
  const float QS = 0.18033688011112042f;  // log2(e)/8
  float bv[NTC];
#pragma unroll
  for (int nt = 0; nt < NTC; ++nt) bv[nt] = bias[n0 + wn * (NT / 2) + nt * 16 + c16];
#pragma unroll
  for (int mt = 0; mt < 4; ++mt) {
#pragma unroll
    for (int nt = 0; nt < NTC; ++nt) {
      const int n = n0 + wn * (NT / 2) + nt * 16 + c16;
#pragma unroll
      for (int r = 0; r < 4; ++r) {
        const int m = m0 + wm * 64 + mt * 16 + quad * 4 + r;
        const size_t idx = (size_t)m * N + n;
        float v = acc[mt][nt][r] + bv[nt];
        if (mode == 2)      { outf[idx] = v + bf2f(residb[idx]); }
        else {
          if (mode == 1 && n < 1024) v *= QS;   // pre-scale Q for exp2 softmax
          outb[idx] = f2bf(v);
        }
      }
    }
  }
}

// ---------------------------------------------------------------------------
// Vt transpose: vT[b][h][d][s] from qkv v-section (64x64 tiles via LDS).
// ---------------------------------------------------------------------------
__global__ __launch_bounds__(256) void vtrans(const ushort* __restrict__ qkv,
                                              ushort* __restrict__ vt) {
  const int sb = blockIdx.x, h = blockIdx.y, b = blockIdx.z;
  __shared__ ushort tile[64][72];
  const int t = threadIdx.x;
  {
    const int row = t >> 3, c8 = (t & 7) * 8;   // rows 0..31 (+32)
    const ushort* src = qkv + (size_t)(b * 2048 + sb * 64 + row) * 3072 + 2048 + h * 64 + c8;
    *(uint4*)&tile[row][c8]      = *(const uint4*)src;
    *(uint4*)&tile[row + 32][c8] = *(const uint4*)(src + 32 * 3072);
  }
  __syncthreads();
  const int d = t >> 2, seg = (t & 3) * 16;
  unsigned wbuf[8];
#pragma unroll
  for (int i = 0; i < 8; ++i)
    wbuf[i] = (unsigned)tile[seg + 2 * i][d] | ((unsigned)tile[seg + 2 * i + 1][d] << 16);
  ushort* dst = vt + (size_t)((b * 16 + h) * 64 + d) * 2048 + sb * 64 + seg;
  *(uint4*)(dst)     = *(uint4*)&wbuf[0];
  *(uint4*)(dst + 8) = *(uint4*)&wbuf[4];
}

// ---------------------------------------------------------------------------
// Flash attention (R6 version). Grid (B*H, S/128): x = b*16+h (XCD-local K/V),
// 4 waves x 32 q-rows, KV tile 128.
//  S^T = K.Q^T -> C[key][q];  P C-layout -> B-frag via one shfl_xor(32);
//  O^T = V^T.P -> C[d][q]; li per lane-half, joined once at the end.
// LDS 32KB (sK plane [dslot8][key128], sV swizzled); 4 blocks/CU.
// ---------------------------------------------------------------------------
__global__ __launch_bounds__(256, 4) void attn_kernel(
    const ushort* __restrict__ qkv, const ushort* __restrict__ vtp,
    ushort* __restrict__ attn_out) {
  const int S = 2048;
  const int bh = blockIdx.x, qblk = blockIdx.y;
  const int h = bh & 15, b = bh >> 4;
  const int t = threadIdx.x, wave = t >> 6, lane = t & 63;
  const int c32 = lane & 31, hi = lane >> 5;
  __shared__ __align__(16) ushort sK[8192];       // 16 KB
  __shared__ __align__(16) ushort sV[8192];       // 16 KB
  const int q0 = qblk * 128;
  const size_t qrow = (size_t)(b * S + q0 + wave * 32 + c32);
  const int swv0 = (c32 ^ (c32 >> 3)) & 15;             // sV swizzle, d=c32
  const int dv1 = 32 + c32;
  const int swv1 = (dv1 ^ (dv1 >> 3)) & 15;             // sV swizzle, d=32+c32
  // Q B-frags: Q[q=lane&31][d = dk*16 + hi*8 + j]  (already scaled by log2e/8)
  bf16x8 qf[4];
  {
    const ushort* qp = qkv + qrow * 3072 + h * 64 + hi * 8;
#pragma unroll
    for (int dk = 0; dk < 4; ++dk) qf[dk] = *(const bf16x8*)(qp + dk * 16);
  }
  f32x16 o0 = {}, o1 = {};
  float li = 0.f;
  const int j0 = wave * 4;

  for (int kv0 = 0; kv0 < S; kv0 += 128) {
    __syncthreads();
#pragma unroll
    for (int c = 0; c < 4; ++c) {
      const int j = j0 + c;
      // sK: slot = dslot*128 + key
      const int dslot = j >> 1, key = (j & 1) * 64 + lane;
      glds16(qkv + (size_t)(b * S + kv0 + key) * 3072 + 1024 + h * 64 + dslot * 8,
             sK + j * 512);
      // sV: lds slot = d*16+ks'; global ks = ks' ^ swz(d)
      const int d = j * 4 + (lane >> 4);
      const int ksv = (lane & 15) ^ ((d ^ (d >> 3)) & 15);
      glds16(vtp + (size_t)((b * 16 + h) * 64 + d) * S + kv0 + ksv * 8,
             sV + j * 512);
    }
    __syncthreads();
#pragma unroll
    for (int kt = 0; kt < 4; ++kt) {
      // S^T tile (32 keys x 32 q)
      f32x16 z = {};
#pragma unroll
      for (int dk = 0; dk < 4; ++dk) {
        bf16x8 kf = *(const bf16x8*)(sK + ((dk * 2 + hi) * 128 + kt * 32 + c32) * 8);
        z = __builtin_amdgcn_mfma_f32_32x32x16_bf16(kf, qf[dk], z, 0, 0, 0);
      }
      // p = exp2(z); accumulate li; pack to bf16 pairs (truncation)
      uint2 w[4];
#pragma unroll
      for (int g = 0; g < 4; ++g) {
        const float p0 = EXP2(z[g * 4 + 0]);
        const float p1 = EXP2(z[g * 4 + 1]);
        const float p2 = EXP2(z[g * 4 + 2]);
        const float p3 = EXP2(z[g * 4 + 3]);
        li += (p0 + p1) + (p2 + p3);
        w[g].x = __builtin_amdgcn_perm(__float_as_uint(p1), __float_as_uint(p0),
                                       0x07060302u);
        w[g].y = __builtin_amdgcn_perm(__float_as_uint(p3), __float_as_uint(p2),
                                       0x07060302u);
      }
      // partner half's packs
      uint2 pp[4];
#pragma unroll
      for (int g = 0; g < 4; ++g) {
        pp[g].x = __shfl_xor((int)w[g].x, 32);
        pp[g].y = __shfl_xor((int)w[g].y, 32);
      }
      // PV: kb = kt*2+e covers keys kt*32 + e*16 + hi*8 + {0..7}
#pragma unroll
      for (int e = 0; e < 2; ++e) {
        const uint2 lo4 = hi ? pp[2 * e + 1] : w[2 * e];
        const uint2 hi4 = hi ? w[2 * e + 1] : pp[2 * e];
        const uint4 fr = make_uint4(lo4.x, lo4.y, hi4.x, hi4.y);
        bf16x8 pf;
        __builtin_memcpy(&pf, &fr, 16);
        const int ksl = kt * 4 + e * 2 + hi;   // 8-key slot within 128
        bf16x8 vf0 = *(const bf16x8*)(sV + (c32 * 16 + (ksl ^ swv0)) * 8);
        o0 = __builtin_amdgcn_mfma_f32_32x32x16_bf16(vf0, pf, o0, 0, 0, 0);
        bf16x8 vf1 = *(const bf16x8*)(sV + (dv1 * 16 + (ksl ^ swv1)) * 8);
        o1 = __builtin_amdgcn_mfma_f32_32x32x16_bf16(vf1, pf, o1, 0, 0, 0);
      }
    }
  }
  // join li across lane halves (each half saw half the keys)
  li += __shfl_xor(li, 32);
  const float inv = 1.f / li;
  ushort* orow = attn_out + qrow * 1024 + h * 64;
#pragma unroll
  for (int dt = 0; dt < 2; ++dt) {
    const f32x16 ov = dt ? o1 : o0;
#pragma unroll
    for (int g = 0; g < 4; ++g) {
      float v0 = ov[g * 4 + 0] * inv, v1 = ov[g * 4 + 1] * inv;
      float v2 = ov[g * 4 + 2] * inv, v3 = ov[g * 4 + 3] * inv;
      uint2 w2;
      w2.x = (unsigned)f2bf(v0) | ((unsigned)f2bf(v1) << 16);
      w2.y = (unsigned)f2bf(v2) | ((unsigned)f2bf(v3) << 16);
      *(uint2*)(orow + dt * 32 + g * 8 + hi * 4) = w2;
    }
  }
}

// ---------------------------------------------------------------------------
// LayerNorm over D=1024 per row.
// ---------------------------------------------------------------------------
__global__ __launch_bounds__(256) void ln_kernel(const float* __restrict__ y,
                                                 const float* __restrict__ g,
                                                 const float* __restrict__ bta,
                                                 float* __restrict__ out) {
  const int m = blockIdx.x;
  const int t = threadIdx.x;
  const float* row = y + (size_t)m * 1024;
  float4 v = ((const float4*)row)[t];
  float s = v.x + v.y + v.z + v.w;
  float s2 = v.x * v.x + v.y * v.y + v.z * v.z + v.w * v.w;
#pragma unroll
  for (int off = 1; off < 64; off <<= 1) {
    s += __shfl_xor(s, off, 64);
    s2 += __shfl_xor(s2, off, 64);
  }
  __shared__ float red[8];
  const int wave = t >> 6, lane = t & 63;
  if (lane == 0) { red[wave] = s; red[4 + wave] = s2; }
  __syncthreads();
  s = red[0] + red[1] + red[2] + red[3];
  s2 = red[4] + red[5] + red[6] + red[7];
  const float mu = s * (1.f / 1024.f);
  const float var = s2 * (1.f / 1024.f) - mu * mu;
  const float rs = rsqrtf(var + 1e-5f);
  float4 gg = ((const float4*)g)[t];
  float4 bb = ((const float4*)bta)[t];
  float4 o;
  o.x = (v.x - mu) * rs * gg.x + bb.x;
  o.y = (v.y - mu) * rs * gg.y + bb.y;
  o.z = (v.z - mu) * rs * gg.z + bb.z;
  o.w = (v.w - mu) * rs * gg.w + bb.w;
  ((float4*)(out + (size_t)m * 1024))[t] = o;
}

// ---------------------------------------------------------------------------
// Workspace (108 MB):
//  [0,48M)   qkvb bf16 [8192][3072]; awin bf16 alias [0,32M) (dead before
//            qkvb); y fp32 alias [0,32M) (qkvb dead after attn)
//  [48,64M)  chunkb bf16
//  [64,80M)  vtb bf16 [B][H][64][S]
//  [80,96M)  attnb bf16 [8192][1024]
//  [96,100M) cwb  [100,106M) ipwb  [106,108M) opwb
// ---------------------------------------------------------------------------
extern "C" void kernel_launch(void* const* d_in, const int* in_sizes, int n_in,
                              void* d_out, int out_size, void* d_ws, size_t ws_size,
                              hipStream_t stream) {
  const float* emb        = (const float*)d_in[0];
  const float* chunk_w    = (const float*)d_in[1];
  const float* chunk_b    = (const float*)d_in[2];
  const float* in_proj_w  = (const float*)d_in[3];
  const float* in_proj_b  = (const float*)d_in[4];
  const float* out_proj_w = (const float*)d_in[5];
  const float* out_proj_b = (const float*)d_in[6];
  const float* ln_g       = (const float*)d_in[7];
  const float* ln_b       = (const float*)d_in[8];

  char* w = (char*)d_ws;
  const size_t MBy = (size_t)1 << 20;
  ushort* qkvb   = (ushort*)(w + 0);
  ushort* awin   = (ushort*)(w + 0);           // dead before qkvb written
  float*  y      = (float*)(w + 0);            // live after attn reads qkvb
  ushort* chunkb = (ushort*)(w + 48 * MBy);
  ushort* vtb    = (ushort*)(w + 64 * MBy);
  ushort* attnb  = (ushort*)(w + 80 * MBy);
  ushort* cwb    = (ushort*)(w + 96 * MBy);
  ushort* ipwb   = (ushort*)(w + 100 * MBy);
  ushort* opwb   = (ushort*)(w + 106 * MBy);

  // Phase 1: bf16 conversions
  build_awin<<<16384, 256, 0, stream>>>(emb, awin);
  cvt_bf16<<<2048, 256, 0, stream>>>(chunk_w, cwb, 2 * 1024 * 1024 / 4);
  cvt_bf16<<<3072, 256, 0, stream>>>(in_proj_w, ipwb, 3 * 1024 * 1024 / 4);
  cvt_bf16<<<1024, 256, 0, stream>>>(out_proj_w, opwb, 1024 * 1024 / 4);

  // Phase 2: chunk = A_win @ chunk_w^T + b  (M=8192 N=1024 K=2048) -> bf16
  gemm_bt<64><<<dim3(8192 / 128, 1024 / 64), 256, 0, stream>>>(
      awin, cwb, chunk_b, 8192, 1024, 2048, 0, nullptr, chunkb, nullptr);

  // Phase 3: qkv = chunk @ in_proj_w^T + b (N=3072 K=1024); Q cols pre-scaled
  gemm_bt<128><<<dim3(8192 / 128, 3072 / 128), 256, 0, stream>>>(
      chunkb, ipwb, in_proj_b, 8192, 3072, 1024, 1, nullptr, qkvb, nullptr);

  // Phase 3b: v^T materialization
  vtrans<<<dim3(32, 16, 4), 256, 0, stream>>>(qkvb, vtb);

  // Phase 4: attention (x = b*16+h for XCD-local K/V; q-tile 128)
  attn_kernel<<<dim3(64, 2048 / 128, 1), 256, 0, stream>>>(qkvb, vtb, attnb);

  // Phase 5: y = attn @ out_proj_w^T + b + chunk  (N=1024 K=1024)
  gemm_bt<64><<<dim3(8192 / 128, 1024 / 64), 256, 0, stream>>>(
      attnb, opwb, out_proj_b, 8192, 1024, 1024, 2, y, nullptr, chunkb);

  // Phase 6: LayerNorm -> d_out
  ln_kernel<<<8192, 256, 0, stream>>>(y, ln_g, ln_b, (float*)d_out);
}

// Round 10
// 455.770 us; speedup vs baseline: 1.0779x; 1.0779x over previous
//
#include <hip/hip_runtime.h>

// ---------------------------------------------------------------------------
// TapeHead R10: windowed chunk proj -> QKV -> MHA -> out proj -> LN.
// B=4 S=2048 D=1024 C=2 H=16, M=8192.
// R10:
//  (a) attn: V-key order permuted (pi: swap 4-blocks at pos 4-7 <-> 8-11 per
//      16) so each lane's packed S^T C-runs ARE the PV B-frag -> the 8
//      ds_bpermute + selects per kt vanish. Only vtrans word order + PV pf
//      construction change.
//  (b) chunk GEMM (gemm_chunk) reads emb directly: chunk = emb[s] W1^T +
//      emb[s+1] W2^T -- two K=1024 terms sharing one 129-row A-tile. Half the
//      K-iterations/barriers of R9's K=2048; awin replaced by embb
//      [4][2049][1024] bf16 with a zero row per batch.
// Everything else identical to R9.
// ---------------------------------------------------------------------------

typedef __bf16 bf16x8 __attribute__((ext_vector_type(8)));
typedef float f32x4 __attribute__((ext_vector_type(4)));
typedef float f32x16 __attribute__((ext_vector_type(16)));

#if __has_builtin(__builtin_amdgcn_exp2f)
#define EXP2(x) __builtin_amdgcn_exp2f(x)
#else
#define EXP2(x) exp2f(x)
#endif

__device__ __forceinline__ unsigned short f2bf(float x) {
  unsigned u = __float_as_uint(x);
  u += 0x7fffu + ((u >> 16) & 1u);
  return (unsigned short)(u >> 16);
}

__device__ __forceinline__ float bf2f(unsigned short x) {
  return __uint_as_float(((unsigned)x) << 16);
}

// async global->LDS, 16B per lane; LDS dest = wave-uniform base + lane*16
__device__ __forceinline__ void glds16(const ushort* g, ushort* l) {
  __builtin_amdgcn_global_load_lds(
      (const __attribute__((address_space(1))) unsigned int*)g,
      (__attribute__((address_space(3))) unsigned int*)l, 16, 0, 0);
}

// ---------------------------------------------------------------------------
// emb fp32 -> embb bf16 [4][2049][1024] (row 2048 of each batch zeroed by
// zrow_kernel).  i indexes float4 groups of the 8192x1024 source.
// ---------------------------------------------------------------------------
__global__ __launch_bounds__(256) void cvt_emb(const float* __restrict__ emb,
                                               ushort* __restrict__ embb) {
  const int i = blockIdx.x * 256 + threadIdx.x;
  const int e = i * 4;                 // source flat elem
  const int m = e >> 10;               // source row
  const int b = m >> 11, s = m & 2047;
  float4 v = *(const float4*)(emb + (size_t)e);
  ushort4 o;
  o.x = f2bf(v.x); o.y = f2bf(v.y); o.z = f2bf(v.z); o.w = f2bf(v.w);
  *(ushort4*)(embb + ((size_t)(b * 2049 + s) << 10) + (e & 1023)) = o;
}

__global__ void zrow_kernel(ushort* __restrict__ embb) {
  const int b = blockIdx.x, t = threadIdx.x;
  ushort4 z = {0, 0, 0, 0};
  *(ushort4*)(embb + ((size_t)(b * 2049 + 2048) << 10) + t * 4) = z;
}

__global__ __launch_bounds__(256) void cvt_bf16(const float* __restrict__ in,
                                                ushort* __restrict__ out, int n4) {
  const int i = blockIdx.x * 256 + threadIdx.x;
  if (i >= n4) return;
  float4 v = ((const float4*)in)[i];
  ushort4 o;
  o.x = f2bf(v.x); o.y = f2bf(v.y); o.z = f2bf(v.z); o.w = f2bf(v.w);
  ((ushort4*)out)[i] = o;
}

// ---------------------------------------------------------------------------
// gemm_chunk: chunk[m][n] = emb[m] . W1[n] + emb[m+1] . W2[n] + bias[n]
// (W1 = chunk_w cols 0..1023, W2 = cols 1024..2047; emb row m+1 via embb's
// per-batch zero row when s==2047).  128x64 tile, 4 waves (2x2), K=1024,
// BK=64 -> 8 iterations.  A-tile = 129 rows (sA 128 + sA2 boundary row).
// Grid: x = mb (XCD-local A rows), y = nb.
// ---------------------------------------------------------------------------
__global__ __launch_bounds__(256) void gemm_chunk(
    const ushort* __restrict__ embb, const ushort* __restrict__ cwb,
    const float* __restrict__ bias, ushort* __restrict__ outb) {
  __shared__ __align__(16) ushort sA[8192];    // 8 kslots x 128 rows x 8
  __shared__ __align__(16) ushort sA2[512];    // boundary row 128, 8 kslots x8
  __shared__ __align__(16) ushort sB1[4096];   // 8 kslots x 64 rows x 8
  __shared__ __align__(16) ushort sB2[4096];
  const int t = threadIdx.x, wave = t >> 6, lane = t & 63;
  const int c16 = lane & 15, quad = lane >> 4;
  const int wm = wave >> 1, wn = wave & 1;
  const int m0 = blockIdx.x * 128, n0 = blockIdx.y * 64;
  const int b = m0 >> 11, s0 = m0 & 2047;
  const size_t rowbase = (size_t)(b * 2049 + s0);
  f32x4 acc[4][2] = {};
  // A staging: 16 calls, j = wave*4+c: kslot=j>>1, row=(j&1)*64+lane
  const ushort* gA[4];
  ushort* lA[4];
#pragma unroll
  for (int c = 0; c < 4; ++c) {
    const int j = wave * 4 + c;
    const int ks = j >> 1, row = (j & 1) * 64 + lane;
    gA[c] = embb + ((rowbase + row) << 10) + ks * 8;
    lA[c] = sA + j * 512;
  }
  // boundary row (wave 3 only): all lanes load row 128, kslot = lane&7
  const ushort* gA2 = embb + ((rowbase + 128) << 10) + (lane & 7) * 8;
  // B staging: 8 calls each; j = wave*2+c: kslot=j, row=lane
  const ushort* gB1[2];
  const ushort* gB2[2];
  ushort* lB1[2];
  ushort* lB2[2];
#pragma unroll
  for (int c = 0; c < 2; ++c) {
    const int j = wave * 2 + c;
    gB1[c] = cwb + (size_t)(n0 + lane) * 2048 + j * 8;
    gB2[c] = gB1[c] + 1024;
    lB1[c] = sB1 + j * 512;
    lB2[c] = sB2 + j * 512;
  }
  for (int k0 = 0; k0 < 1024; k0 += 64) {
    __syncthreads();
#pragma unroll
    for (int c = 0; c < 4; ++c) glds16(gA[c] + k0, lA[c]);
    if (wave == 3) glds16(gA2 + k0, sA2);
#pragma unroll
    for (int c = 0; c < 2; ++c) {
      glds16(gB1[c] + k0, lB1[c]);
      glds16(gB2[c] + k0, lB2[c]);
    }
    __syncthreads();
#pragma unroll
    for (int kc = 0; kc < 2; ++kc) {
      const int ksl = kc * 4 + quad;
      bf16x8 af1[4], af2[4], bf1[2], bf2[2];
#pragma unroll
      for (int i = 0; i < 4; ++i) {
        const int row = wm * 64 + i * 16 + c16;
        af1[i] = *(const bf16x8*)(sA + (ksl * 128 + row) * 8);
        const ushort* p2 = (row + 1 < 128) ? (sA + (ksl * 128 + row + 1) * 8)
                                           : (sA2 + ksl * 8);
        af2[i] = *(const bf16x8*)p2;
      }
#pragma unroll
      for (int i = 0; i < 2; ++i) {
        bf1[i] = *(const bf16x8*)(sB1 + (ksl * 64 + wn * 32 + i * 16 + c16) * 8);
        bf2[i] = *(const bf16x8*)(sB2 + (ksl * 64 + wn * 32 + i * 16 + c16) * 8);
      }
#pragma unroll
      for (int mt = 0; mt < 4; ++mt)
#pragma unroll
        for (int nt = 0; nt < 2; ++nt) {
          acc[mt][nt] = __builtin_amdgcn_mfma_f32_16x16x32_bf16(af1[mt], bf1[nt],
                                                                acc[mt][nt], 0, 0, 0);
          acc[mt][nt] = __builtin_amdgcn_mfma_f32_16x16x32_bf16(af2[mt], bf2[nt],
                                                                acc[mt][nt], 0, 0, 0);
        }
    }
  }
  float bv[2];
#pragma unroll
  for (int nt = 0; nt < 2; ++nt) bv[nt] = bias[n0 + wn * 32 + nt * 16 + c16];
#pragma unroll
  for (int mt = 0; mt < 4; ++mt)
#pragma unroll
    for (int nt = 0; nt < 2; ++nt) {
      const int n = n0 + wn * 32 + nt * 16 + c16;
#pragma unroll
      for (int r = 0; r < 4; ++r) {
        const int m = m0 + wm * 64 + mt * 16 + quad * 4 + r;
        outb[(size_t)m * 1024 + n] = f2bf(acc[mt][nt][r] + bv[nt]);
      }
    }
}

// ---------------------------------------------------------------------------
// gemm_bt<NT>: C[m][n] = sum_k A[m][k]*W[n][k] + bias[n]; 128xNT tile, 4 waves
// (2x2), 16x16x32 MFMA, BK=64, plane layout [kslot][row] (slot = 16B).
// Grid: x = mb, y = nb (XCD = mb%8 keeps A-tile L2-local).
// Modes: 1: outb bf16, cols n<1024 pre-scaled by log2(e)/8 (Q);
//        2: outf = acc + bias + bf2f(residb).
// ---------------------------------------------------------------------------
template <int NT>
__global__ __launch_bounds__(256) void gemm_bt(
    const ushort* __restrict__ A, const ushort* __restrict__ W,
    const float* __restrict__ bias, int M, int N, int K, int mode,
    float* __restrict__ outf, ushort* __restrict__ outb,
    const ushort* __restrict__ residb) {
  constexpr int NTC = NT / 32;
  constexpr int BC  = NT / 32;
  __shared__ __align__(16) ushort sA[8192];
  __shared__ __align__(16) ushort sB[NT * 64];
  const int t = threadIdx.x, wave = t >> 6, lane = t & 63;
  const int c16 = lane & 15, quad = lane >> 4;
  const int wm = wave >> 1, wn = wave & 1;
  const int m0 = blockIdx.x * 128, n0 = blockIdx.y * NT;
  f32x4 acc[4][NTC] = {};
  const ushort* gA[4];
  const ushort* gB[BC];
  ushort* lA[4];
  ushort* lB[BC];
#pragma unroll
  for (int c = 0; c < 4; ++c) {
    const int j = wave * 4 + c;
    const int ks = j >> 1, row = (j & 1) * 64 + lane;
    gA[c] = A + (size_t)(m0 + row) * K + ks * 8;
    lA[c] = sA + j * 512;
  }
#pragma unroll
  for (int c = 0; c < BC; ++c) {
    const int j = wave * BC + c;
    int ksb, rowb;
    if (NT == 128) { ksb = j >> 1; rowb = (j & 1) * 64 + lane; }
    else           { ksb = j;      rowb = lane; }
    gB[c] = W + (size_t)(n0 + rowb) * K + ksb * 8;
    lB[c] = sB + j * 512;
  }
  for (int k0 = 0; k0 < K; k0 += 64) {
    __syncthreads();
#pragma unroll
    for (int c = 0; c < 4; ++c) glds16(gA[c] + k0, lA[c]);
#pragma unroll
    for (int c = 0; c < BC; ++c) glds16(gB[c] + k0, lB[c]);
    __syncthreads();
#pragma unroll
    for (int kc = 0; kc < 2; ++kc) {
      bf16x8 af[4], bfr[NTC];
#pragma unroll
      for (int i = 0; i < 4; ++i)
        af[i] = *(const bf16x8*)(sA + ((kc * 4 + quad) * 128 + wm * 64 + i * 16 + c16) * 8);
#pragma unroll
      for (int i = 0; i < NTC; ++i)
        bfr[i] = *(const bf16x8*)(sB + ((kc * 4 + quad) * NT + wn * (NT / 2) + i * 16 + c16) * 8);
#pragma unroll
      for (int mt = 0; mt < 4; ++mt)
#pragma unroll
        for (int nt = 0; nt < NTC; ++nt)
          acc[mt][nt] = __builtin_amdgcn_mfma_f32_16x16x32_bf16(af[mt], bfr[nt],
                                                                acc[mt][nt], 0, 0, 0);
    }
  }
  const float QS = 0.18033688011112042f;  // log2(e)/8
  float bv[NTC];
#pragma unroll
  for (int nt = 0; nt < NTC; ++nt) bv[nt] = bias[n0 + wn * (NT / 2) + nt * 16 + c16];
#pragma unroll
  for (int mt = 0; mt < 4; ++mt) {
#pragma unroll
    for (int nt = 0; nt < NTC; ++nt) {
      const int n = n0 + wn * (NT / 2) + nt * 16 + c16;
#pragma unroll
      for (int r = 0; r < 4; ++r) {
        const int m = m0 + wm * 64 + mt * 16 + quad * 4 + r;
        const size_t idx = (size_t)m * N + n;
        float v = acc[mt][nt][r] + bv[nt];
        if (mode == 2)      { outf[idx] = v + bf2f(residb[idx]); }
        else {
          if (n < 1024) v *= QS;   // pre-scale Q for exp2 softmax
          outb[idx] = f2bf(v);
        }
      }
    }
  }
}

// ---------------------------------------------------------------------------
// Vt transpose: vT[b][h][d][s'] from qkv v-section, with the PV key
// permutation pi baked in: within each 16-key block, output word order is
// w0,w1,w4,w5,w2,w3,w6,w7 (swap key-pairs 4-7 <-> 8-11).
// ---------------------------------------------------------------------------
__global__ __launch_bounds__(256) void vtrans(const ushort* __restrict__ qkv,
                                              ushort* __restrict__ vt) {
  const int sb = blockIdx.x, h = blockIdx.y, b = blockIdx.z;
  __shared__ ushort tile[64][72];
  const int t = threadIdx.x;
  {
    const int row = t >> 3, c8 = (t & 7) * 8;   // rows 0..31 (+32)
    const ushort* src = qkv + (size_t)(b * 2048 + sb * 64 + row) * 3072 + 2048 + h * 64 + c8;
    *(uint4*)&tile[row][c8]      = *(const uint4*)src;
    *(uint4*)&tile[row + 32][c8] = *(const uint4*)(src + 32 * 3072);
  }
  __syncthreads();
  const int d = t >> 2, seg = (t & 3) * 16;
  unsigned wbuf[8];
#pragma unroll
  for (int i = 0; i < 8; ++i)
    wbuf[i] = (unsigned)tile[seg + 2 * i][d] | ((unsigned)tile[seg + 2 * i + 1][d] << 16);
  ushort* dst = vt + (size_t)((b * 16 + h) * 64 + d) * 2048 + sb * 64 + seg;
  // pi permutation: positions 4-7 <- keys 8-11 (w4,w5), positions 8-11 <- keys
  // 4-7 (w2,w3)
  uint4 oA = make_uint4(wbuf[0], wbuf[1], wbuf[4], wbuf[5]);
  uint4 oB = make_uint4(wbuf[2], wbuf[3], wbuf[6], wbuf[7]);
  *(uint4*)(dst)     = oA;
  *(uint4*)(dst + 8) = oB;
}

// ---------------------------------------------------------------------------
// Flash attention. Grid (B*H, S/128): x = b*16+h (XCD-local K/V), 4 waves x
// 32 q-rows, KV tile 128.
//  S^T = K.Q^T -> C[key][q]; reg-run g packs keys 8g+4hi+{0..3} (w[g]).
//  PV: with sV keys in pi order, B-frag for chunk c IS (w[2c], w[2c+1]) --
//  register-direct, no cross-lane exchange.
// LDS 32KB (sK plane [dslot8][key128], sV swizzled); 4 blocks/CU.
// Fixed-max exp2 softmax (Q pre-scaled); li per lane-half, joined at end.
// ---------------------------------------------------------------------------
__global__ __launch_bounds__(256, 4) void attn_kernel(
    const ushort* __restrict__ qkv, const ushort* __restrict__ vtp,
    ushort* __restrict__ attn_out) {
  const int S = 2048;
  const int bh = blockIdx.x, qblk = blockIdx.y;
  const int h = bh & 15, b = bh >> 4;
  const int t = threadIdx.x, wave = t >> 6, lane = t & 63;
  const int c32 = lane & 31, hi = lane >> 5;
  __shared__ __align__(16) ushort sK[8192];       // 16 KB
  __shared__ __align__(16) ushort sV[8192];       // 16 KB
  const int q0 = qblk * 128;
  const size_t qrow = (size_t)(b * S + q0 + wave * 32 + c32);
  const int swv0 = (c32 ^ (c32 >> 3)) & 15;             // sV swizzle, d=c32
  const int dv1 = 32 + c32;
  const int swv1 = (dv1 ^ (dv1 >> 3)) & 15;             // sV swizzle, d=32+c32
  // Q B-frags: Q[q=lane&31][d = dk*16 + hi*8 + j]  (already scaled by log2e/8)
  bf16x8 qf[4];
  {
    const ushort* qp = qkv + qrow * 3072 + h * 64 + hi * 8;
#pragma unroll
    for (int dk = 0; dk < 4; ++dk) qf[dk] = *(const bf16x8*)(qp + dk * 16);
  }
  f32x16 o0 = {}, o1 = {};
  float li = 0.f;
  const int j0 = wave * 4;

  for (int kv0 = 0; kv0 < S; kv0 += 128) {
    __syncthreads();
#pragma unroll
    for (int c = 0; c < 4; ++c) {
      const int j = j0 + c;
      // sK: slot = dslot*128 + key
      const int dslot = j >> 1, key = (j & 1) * 64 + lane;
      glds16(qkv + (size_t)(b * S + kv0 + key) * 3072 + 1024 + h * 64 + dslot * 8,
             sK + j * 512);
      // sV: lds slot = d*16+ks'; global ks = ks' ^ swz(d)  (keys pi-ordered)
      const int d = j * 4 + (lane >> 4);
      const int ksv = (lane & 15) ^ ((d ^ (d >> 3)) & 15);
      glds16(vtp + (size_t)((b * 16 + h) * 64 + d) * S + kv0 + ksv * 8,
             sV + j * 512);
    }
    __syncthreads();
#pragma unroll
    for (int kt = 0; kt < 4; ++kt) {
      // S^T tile (32 keys x 32 q)
      f32x16 z = {};
#pragma unroll
      for (int dk = 0; dk < 4; ++dk) {
        bf16x8 kf = *(const bf16x8*)(sK + ((dk * 2 + hi) * 128 + kt * 32 + c32) * 8);
        z = __builtin_amdgcn_mfma_f32_32x32x16_bf16(kf, qf[dk], z, 0, 0, 0);
      }
      // p = exp2(z); accumulate li; pack runs to bf16 (w[g]: keys 8g+4hi+..)
      uint2 w[4];
#pragma unroll
      for (int g = 0; g < 4; ++g) {
        const float p0 = EXP2(z[g * 4 + 0]);
        const float p1 = EXP2(z[g * 4 + 1]);
        const float p2 = EXP2(z[g * 4 + 2]);
        const float p3 = EXP2(z[g * 4 + 3]);
        li += (p0 + p1) + (p2 + p3);
        w[g].x = __builtin_amdgcn_perm(__float_as_uint(p1), __float_as_uint(p0),
                                       0x07060302u);
        w[g].y = __builtin_amdgcn_perm(__float_as_uint(p3), __float_as_uint(p2),
                                       0x07060302u);
      }
      // PV: chunk c in {0,1}; B-frag = (w[2c], w[2c+1]) directly (pi order)
#pragma unroll
      for (int c = 0; c < 2; ++c) {
        const uint4 fr = make_uint4(w[2 * c].x, w[2 * c].y,
                                    w[2 * c + 1].x, w[2 * c + 1].y);
        bf16x8 pf;
        __builtin_memcpy(&pf, &fr, 16);
        const int ksl = kt * 4 + c * 2 + hi;   // 8-key slot within 128
        bf16x8 vf0 = *(const bf16x8*)(sV + (c32 * 16 + (ksl ^ swv0)) * 8);
        o0 = __builtin_amdgcn_mfma_f32_32x32x16_bf16(vf0, pf, o0, 0, 0, 0);
        bf16x8 vf1 = *(const bf16x8*)(sV + (dv1 * 16 + (ksl ^ swv1)) * 8);
        o1 = __builtin_amdgcn_mfma_f32_32x32x16_bf16(vf1, pf, o1, 0, 0, 0);
      }
    }
  }
  // join li across lane halves (each half saw half the keys)
  li += __shfl_xor(li, 32);
  const float inv = 1.f / li;
  ushort* orow = attn_out + qrow * 1024 + h * 64;
#pragma unroll
  for (int dt = 0; dt < 2; ++dt) {
    const f32x16 ov = dt ? o1 : o0;
#pragma unroll
    for (int g = 0; g < 4; ++g) {
      float v0 = ov[g * 4 + 0] * inv, v1 = ov[g * 4 + 1] * inv;
      float v2 = ov[g * 4 + 2] * inv, v3 = ov[g * 4 + 3] * inv;
      uint2 w2;
      w2.x = (unsigned)f2bf(v0) | ((unsigned)f2bf(v1) << 16);
      w2.y = (unsigned)f2bf(v2) | ((unsigned)f2bf(v3) << 16);
      *(uint2*)(orow + dt * 32 + g * 8 + hi * 4) = w2;
    }
  }
}

// ---------------------------------------------------------------------------
// LayerNorm over D=1024 per row.
// ---------------------------------------------------------------------------
__global__ __launch_bounds__(256) void ln_kernel(const float* __restrict__ y,
                                                 const float* __restrict__ g,
                                                 const float* __restrict__ bta,
                                                 float* __restrict__ out) {
  const int m = blockIdx.x;
  const int t = threadIdx.x;
  const float* row = y + (size_t)m * 1024;
  float4 v = ((const float4*)row)[t];
  float s = v.x + v.y + v.z + v.w;
  float s2 = v.x * v.x + v.y * v.y + v.z * v.z + v.w * v.w;
#pragma unroll
  for (int off = 1; off < 64; off <<= 1) {
    s += __shfl_xor(s, off, 64);
    s2 += __shfl_xor(s2, off, 64);
  }
  __shared__ float red[8];
  const int wave = t >> 6, lane = t & 63;
  if (lane == 0) { red[wave] = s; red[4 + wave] = s2; }
  __syncthreads();
  s = red[0] + red[1] + red[2] + red[3];
  s2 = red[4] + red[5] + red[6] + red[7];
  const float mu = s * (1.f / 1024.f);
  const float var = s2 * (1.f / 1024.f) - mu * mu;
  const float rs = rsqrtf(var + 1e-5f);
  float4 gg = ((const float4*)g)[t];
  float4 bb = ((const float4*)bta)[t];
  float4 o;
  o.x = (v.x - mu) * rs * gg.x + bb.x;
  o.y = (v.y - mu) * rs * gg.y + bb.y;
  o.z = (v.z - mu) * rs * gg.z + bb.z;
  o.w = (v.w - mu) * rs * gg.w + bb.w;
  ((float4*)(out + (size_t)m * 1024))[t] = o;
}

// ---------------------------------------------------------------------------
// Workspace (125 MB):
//  [0,17M)    embb bf16 [4][2049][1024]   (dead after gemm_chunk)
//  [17,65M)   qkvb bf16 [8192][3072]; y fp32 alias [17,49M) (qkvb dead
//             after attn)
//  [65,81M)   chunkb bf16
//  [81,97M)   vtb bf16 [B][H][64][S] (pi key order)
//  [97,113M)  attnb bf16 [8192][1024]
//  [113,117M) cwb  [117,123M) ipwb  [123,125M) opwb
// ---------------------------------------------------------------------------
extern "C" void kernel_launch(void* const* d_in, const int* in_sizes, int n_in,
                              void* d_out, int out_size, void* d_ws, size_t ws_size,
                              hipStream_t stream) {
  const float* emb        = (const float*)d_in[0];
  const float* chunk_w    = (const float*)d_in[1];
  const float* chunk_b    = (const float*)d_in[2];
  const float* in_proj_w  = (const float*)d_in[3];
  const float* in_proj_b  = (const float*)d_in[4];
  const float* out_proj_w = (const float*)d_in[5];
  const float* out_proj_b = (const float*)d_in[6];
  const float* ln_g       = (const float*)d_in[7];
  const float* ln_b       = (const float*)d_in[8];

  char* w = (char*)d_ws;
  const size_t MBy = (size_t)1 << 20;
  ushort* embb   = (ushort*)(w + 0);
  ushort* qkvb   = (ushort*)(w + 17 * MBy);
  float*  y      = (float*)(w + 17 * MBy);     // alias: live after attn
  ushort* chunkb = (ushort*)(w + 65 * MBy);
  ushort* vtb    = (ushort*)(w + 81 * MBy);
  ushort* attnb  = (ushort*)(w + 97 * MBy);
  ushort* cwb    = (ushort*)(w + 113 * MBy);
  ushort* ipwb   = (ushort*)(w + 117 * MBy);
  ushort* opwb   = (ushort*)(w + 123 * MBy);

  // Phase 1: bf16 conversions (+ per-batch zero row in embb)
  cvt_emb<<<8192, 256, 0, stream>>>(emb, embb);
  zrow_kernel<<<4, 256, 0, stream>>>(embb);
  cvt_bf16<<<2048, 256, 0, stream>>>(chunk_w, cwb, 2 * 1024 * 1024 / 4);
  cvt_bf16<<<3072, 256, 0, stream>>>(in_proj_w, ipwb, 3 * 1024 * 1024 / 4);
  cvt_bf16<<<1024, 256, 0, stream>>>(out_proj_w, opwb, 1024 * 1024 / 4);

  // Phase 2: chunk = emb[s] W1^T + emb[s+1] W2^T + b  (K=1024 x 2 terms)
  gemm_chunk<<<dim3(8192 / 128, 1024 / 64), 256, 0, stream>>>(
      embb, cwb, chunk_b, chunkb);

  // Phase 3: qkv = chunk @ in_proj_w^T + b (N=3072 K=1024); Q cols pre-scaled
  gemm_bt<128><<<dim3(8192 / 128, 3072 / 128), 256, 0, stream>>>(
      chunkb, ipwb, in_proj_b, 8192, 3072, 1024, 1, nullptr, qkvb, nullptr);

  // Phase 3b: v^T materialization (pi key order)
  vtrans<<<dim3(32, 16, 4), 256, 0, stream>>>(qkvb, vtb);

  // Phase 4: attention (x = b*16+h for XCD-local K/V; q-tile 128)
  attn_kernel<<<dim3(64, 2048 / 128, 1), 256, 0, stream>>>(qkvb, vtb, attnb);

  // Phase 5: y = attn @ out_proj_w^T + b + chunk  (N=1024 K=1024)
  gemm_bt<64><<<dim3(8192 / 128, 1024 / 64), 256, 0, stream>>>(
      attnb, opwb, out_proj_b, 8192, 1024, 1024, 2, y, nullptr, chunkb);

  // Phase 6: LayerNorm -> d_out
  ln_kernel<<<8192, 256, 0, stream>>>(y, ln_g, ln_b, (float*)d_out);
}

// Round 11
// 427.513 us; speedup vs baseline: 1.1491x; 1.0661x over previous
//
#include <hip/hip_runtime.h>

// ---------------------------------------------------------------------------
// TapeHead R11: windowed chunk proj -> QKV -> MHA -> out proj -> LN.
// B=4 S=2048 D=1024 C=2 H=16, M=8192.
// R11 (pipeline-overhead harvest):
//  (a) vtrans eliminated: QKV gemm epilogue writes V^T directly to vtb in pi
//      order (r-run = 4 consecutive s; pi permutes aligned 4-blocks: s^12
//      when blk2 in {1,2}); qkvb shrinks to [8192][2048] (q,k only).
//  (b) all dtype conversions merged into one cvt_all launch.
//  (c) phase5 output y in bf16; LN reads bf16 (halves LN input traffic).
// GEMM cores / attn math unchanged from R10.
// ---------------------------------------------------------------------------

typedef __bf16 bf16x8 __attribute__((ext_vector_type(8)));
typedef float f32x4 __attribute__((ext_vector_type(4)));
typedef float f32x16 __attribute__((ext_vector_type(16)));

#if __has_builtin(__builtin_amdgcn_exp2f)
#define EXP2(x) __builtin_amdgcn_exp2f(x)
#else
#define EXP2(x) exp2f(x)
#endif

__device__ __forceinline__ unsigned short f2bf(float x) {
  unsigned u = __float_as_uint(x);
  u += 0x7fffu + ((u >> 16) & 1u);
  return (unsigned short)(u >> 16);
}

__device__ __forceinline__ float bf2f(unsigned short x) {
  return __uint_as_float(((unsigned)x) << 16);
}

// async global->LDS, 16B per lane; LDS dest = wave-uniform base + lane*16
__device__ __forceinline__ void glds16(const ushort* g, ushort* l) {
  __builtin_amdgcn_global_load_lds(
      (const __attribute__((address_space(1))) unsigned int*)g,
      (__attribute__((address_space(3))) unsigned int*)l, 16, 0, 0);
}

// ---------------------------------------------------------------------------
// cvt_all: every fp32->bf16 conversion in one launch (blockIdx ranges):
//  [0,8192)      emb -> embb [4][2049][1024]
//  [8192,8196)   zero row 2048 of each embb batch
//  [8196,10244)  chunk_w  (2M elems)
//  [10244,13316) in_proj_w (3M elems)
//  [13316,14340) out_proj_w (1M elems)
// ---------------------------------------------------------------------------
__global__ __launch_bounds__(256) void cvt_all(
    const float* __restrict__ emb, const float* __restrict__ cw,
    const float* __restrict__ ipw, const float* __restrict__ opw,
    ushort* __restrict__ embb, ushort* __restrict__ cwb,
    ushort* __restrict__ ipwb, ushort* __restrict__ opwb) {
  const int blk = blockIdx.x, t = threadIdx.x;
  if (blk < 8192) {
    const int i = blk * 256 + t;
    const int e = i * 4;
    const int m = e >> 10;
    const int b = m >> 11, s = m & 2047;
    float4 v = *(const float4*)(emb + (size_t)e);
    ushort4 o;
    o.x = f2bf(v.x); o.y = f2bf(v.y); o.z = f2bf(v.z); o.w = f2bf(v.w);
    *(ushort4*)(embb + ((size_t)(b * 2049 + s) << 10) + (e & 1023)) = o;
  } else if (blk < 8196) {
    const int b = blk - 8192;
    ushort4 z = {0, 0, 0, 0};
    *(ushort4*)(embb + ((size_t)(b * 2049 + 2048) << 10) + t * 4) = z;
  } else {
    const float* src;
    ushort* dst;
    int i;
    if (blk < 10244)      { src = cw;  dst = cwb;  i = (blk - 8196) * 256 + t; }
    else if (blk < 13316) { src = ipw; dst = ipwb; i = (blk - 10244) * 256 + t; }
    else                  { src = opw; dst = opwb; i = (blk - 13316) * 256 + t; }
    float4 v = ((const float4*)src)[i];
    ushort4 o;
    o.x = f2bf(v.x); o.y = f2bf(v.y); o.z = f2bf(v.z); o.w = f2bf(v.w);
    ((ushort4*)dst)[i] = o;
  }
}

// ---------------------------------------------------------------------------
// gemm_chunk: chunk[m][n] = emb[m].W1[n] + emb[m+1].W2[n] + bias[n]
// 128x64 tile, 4 waves (2x2), K=1024, BK=64; 129-row A-tile (sA + sA2).
// Grid: x = mb (XCD-local A rows), y = nb.
// ---------------------------------------------------------------------------
__global__ __launch_bounds__(256) void gemm_chunk(
    const ushort* __restrict__ embb, const ushort* __restrict__ cwb,
    const float* __restrict__ bias, ushort* __restrict__ outb) {
  __shared__ __align__(16) ushort sA[8192];
  __shared__ __align__(16) ushort sA2[512];
  __shared__ __align__(16) ushort sB1[4096];
  __shared__ __align__(16) ushort sB2[4096];
  const int t = threadIdx.x, wave = t >> 6, lane = t & 63;
  const int c16 = lane & 15, quad = lane >> 4;
  const int wm = wave >> 1, wn = wave & 1;
  const int m0 = blockIdx.x * 128, n0 = blockIdx.y * 64;
  const int b = m0 >> 11, s0 = m0 & 2047;
  const size_t rowbase = (size_t)(b * 2049 + s0);
  f32x4 acc[4][2] = {};
  const ushort* gA[4];
  ushort* lA[4];
#pragma unroll
  for (int c = 0; c < 4; ++c) {
    const int j = wave * 4 + c;
    const int ks = j >> 1, row = (j & 1) * 64 + lane;
    gA[c] = embb + ((rowbase + row) << 10) + ks * 8;
    lA[c] = sA + j * 512;
  }
  const ushort* gA2 = embb + ((rowbase + 128) << 10) + (lane & 7) * 8;
  const ushort* gB1[2];
  const ushort* gB2[2];
  ushort* lB1[2];
  ushort* lB2[2];
#pragma unroll
  for (int c = 0; c < 2; ++c) {
    const int j = wave * 2 + c;
    gB1[c] = cwb + (size_t)(n0 + lane) * 2048 + j * 8;
    gB2[c] = gB1[c] + 1024;
    lB1[c] = sB1 + j * 512;
    lB2[c] = sB2 + j * 512;
  }
  for (int k0 = 0; k0 < 1024; k0 += 64) {
    __syncthreads();
#pragma unroll
    for (int c = 0; c < 4; ++c) glds16(gA[c] + k0, lA[c]);
    if (wave == 3) glds16(gA2 + k0, sA2);
#pragma unroll
    for (int c = 0; c < 2; ++c) {
      glds16(gB1[c] + k0, lB1[c]);
      glds16(gB2[c] + k0, lB2[c]);
    }
    __syncthreads();
#pragma unroll
    for (int kc = 0; kc < 2; ++kc) {
      const int ksl = kc * 4 + quad;
      bf16x8 af1[4], af2[4], bf1[2], bf2[2];
#pragma unroll
      for (int i = 0; i < 4; ++i) {
        const int row = wm * 64 + i * 16 + c16;
        af1[i] = *(const bf16x8*)(sA + (ksl * 128 + row) * 8);
        const ushort* p2 = (row + 1 < 128) ? (sA + (ksl * 128 + row + 1) * 8)
                                           : (sA2 + ksl * 8);
        af2[i] = *(const bf16x8*)p2;
      }
#pragma unroll
      for (int i = 0; i < 2; ++i) {
        bf1[i] = *(const bf16x8*)(sB1 + (ksl * 64 + wn * 32 + i * 16 + c16) * 8);
        bf2[i] = *(const bf16x8*)(sB2 + (ksl * 64 + wn * 32 + i * 16 + c16) * 8);
      }
#pragma unroll
      for (int mt = 0; mt < 4; ++mt)
#pragma unroll
        for (int nt = 0; nt < 2; ++nt) {
          acc[mt][nt] = __builtin_amdgcn_mfma_f32_16x16x32_bf16(af1[mt], bf1[nt],
                                                                acc[mt][nt], 0, 0, 0);
          acc[mt][nt] = __builtin_amdgcn_mfma_f32_16x16x32_bf16(af2[mt], bf2[nt],
                                                                acc[mt][nt], 0, 0, 0);
        }
    }
  }
  float bv[2];
#pragma unroll
  for (int nt = 0; nt < 2; ++nt) bv[nt] = bias[n0 + wn * 32 + nt * 16 + c16];
#pragma unroll
  for (int mt = 0; mt < 4; ++mt)
#pragma unroll
    for (int nt = 0; nt < 2; ++nt) {
      const int n = n0 + wn * 32 + nt * 16 + c16;
#pragma unroll
      for (int r = 0; r < 4; ++r) {
        const int m = m0 + wm * 64 + mt * 16 + quad * 4 + r;
        outb[(size_t)m * 1024 + n] = f2bf(acc[mt][nt][r] + bv[nt]);
      }
    }
}

// ---------------------------------------------------------------------------
// gemm_bt<NT>: C[m][n] = sum_k A[m][k]*W[n][k] + bias[n]; 128xNT tile, 4 waves
// (2x2), 16x16x32 MFMA, BK=64, plane layout [kslot][row] (slot = 16B).
// Grid: x = mb, y = nb (XCD = mb%8 keeps A-tile L2-local).
// mode 1 (QKV, N=3072): n<1024 -> qkvb[m*2048+n] * log2(e)/8 (Q);
//   1024<=n<2048 -> qkvb[m*2048+n] (K); n>=2048 -> V^T to vtb, pi key order,
//   packed uint2 across the 4-r run (4 consecutive s).
// mode 2: outb[m*N+n] = bf16(acc + bias + bf2f(residb)).
// ---------------------------------------------------------------------------
template <int NT>
__global__ __launch_bounds__(256) void gemm_bt(
    const ushort* __restrict__ A, const ushort* __restrict__ W,
    const float* __restrict__ bias, int M, int N, int K, int mode,
    ushort* __restrict__ outb, const ushort* __restrict__ residb,
    ushort* __restrict__ vtb) {
  constexpr int NTC = NT / 32;
  constexpr int BC  = NT / 32;
  __shared__ __align__(16) ushort sA[8192];
  __shared__ __align__(16) ushort sB[NT * 64];
  const int t = threadIdx.x, wave = t >> 6, lane = t & 63;
  const int c16 = lane & 15, quad = lane >> 4;
  const int wm = wave >> 1, wn = wave & 1;
  const int m0 = blockIdx.x * 128, n0 = blockIdx.y * NT;
  f32x4 acc[4][NTC] = {};
  const ushort* gA[4];
  const ushort* gB[BC];
  ushort* lA[4];
  ushort* lB[BC];
#pragma unroll
  for (int c = 0; c < 4; ++c) {
    const int j = wave * 4 + c;
    const int ks = j >> 1, row = (j & 1) * 64 + lane;
    gA[c] = A + (size_t)(m0 + row) * K + ks * 8;
    lA[c] = sA + j * 512;
  }
#pragma unroll
  for (int c = 0; c < BC; ++c) {
    const int j = wave * BC + c;
    int ksb, rowb;
    if (NT == 128) { ksb = j >> 1; rowb = (j & 1) * 64 + lane; }
    else           { ksb = j;      rowb = lane; }
    gB[c] = W + (size_t)(n0 + rowb) * K + ksb * 8;
    lB[c] = sB + j * 512;
  }
  for (int k0 = 0; k0 < K; k0 += 64) {
    __syncthreads();
#pragma unroll
    for (int c = 0; c < 4; ++c) glds16(gA[c] + k0, lA[c]);
#pragma unroll
    for (int c = 0; c < BC; ++c) glds16(gB[c] + k0, lB[c]);
    __syncthreads();
#pragma unroll
    for (int kc = 0; kc < 2; ++kc) {
      bf16x8 af[4], bfr[NTC];
#pragma unroll
      for (int i = 0; i < 4; ++i)
        af[i] = *(const bf16x8*)(sA + ((kc * 4 + quad) * 128 + wm * 64 + i * 16 + c16) * 8);
#pragma unroll
      for (int i = 0; i < NTC; ++i)
        bfr[i] = *(const bf16x8*)(sB + ((kc * 4 + quad) * NT + wn * (NT / 2) + i * 16 + c16) * 8);
#pragma unroll
      for (int mt = 0; mt < 4; ++mt)
#pragma unroll
        for (int nt = 0; nt < NTC; ++nt)
          acc[mt][nt] = __builtin_amdgcn_mfma_f32_16x16x32_bf16(af[mt], bfr[nt],
                                                                acc[mt][nt], 0, 0, 0);
    }
  }
  const float QS = 0.18033688011112042f;  // log2(e)/8
  float bv[NTC];
#pragma unroll
  for (int nt = 0; nt < NTC; ++nt) bv[nt] = bias[n0 + wn * (NT / 2) + nt * 16 + c16];
#pragma unroll
  for (int mt = 0; mt < 4; ++mt) {
#pragma unroll
    for (int nt = 0; nt < NTC; ++nt) {
      const int n = n0 + wn * (NT / 2) + nt * 16 + c16;
      const int mb = m0 + wm * 64 + mt * 16 + quad * 4;    // base m of the r-run
      if (mode == 2) {
#pragma unroll
        for (int r = 0; r < 4; ++r) {
          const size_t idx = (size_t)(mb + r) * N + n;
          outb[idx] = f2bf(acc[mt][nt][r] + bv[nt] + bf2f(residb[idx]));
        }
      } else if (n < 2048) {
        const float sc = (n < 1024) ? QS : 1.f;
#pragma unroll
        for (int r = 0; r < 4; ++r)
          outb[(size_t)(mb + r) * 2048 + n] = f2bf((acc[mt][nt][r] + bv[nt]) * sc);
      } else {
        // V^T write, pi key order (swap aligned 4-blocks 1<->2 within each 16)
        const int d = n - 2048, h = d >> 6, dd = d & 63;
        const int b = mb >> 11, s = mb & 2047;
        const int blk2 = (s >> 2) & 3;
        const int sp = (blk2 == 1 || blk2 == 2) ? (s ^ 12) : s;
        uint2 w2;
        w2.x = (unsigned)f2bf(acc[mt][nt][0] + bv[nt]) |
               ((unsigned)f2bf(acc[mt][nt][1] + bv[nt]) << 16);
        w2.y = (unsigned)f2bf(acc[mt][nt][2] + bv[nt]) |
               ((unsigned)f2bf(acc[mt][nt][3] + bv[nt]) << 16);
        *(uint2*)(vtb + (size_t)((b * 16 + h) * 64 + dd) * 2048 + sp) = w2;
      }
    }
  }
}

// ---------------------------------------------------------------------------
// Flash attention. Grid (B*H, S/128): x = b*16+h (XCD-local K/V), 4 waves x
// 32 q-rows, KV tile 128.  qkv stride 2048 (Q at +0, K at +1024, per-head 64).
//  S^T = K.Q^T -> C[key][q]; reg-run g packs keys 8g+4hi+{0..3} (w[g]).
//  PV: sV keys in pi order -> B-frag for chunk c IS (w[2c], w[2c+1]).
// LDS 32KB (sK plane [dslot8][key128], sV swizzled); 4 blocks/CU.
// Fixed-max exp2 softmax (Q pre-scaled); li per lane-half, joined at end.
// ---------------------------------------------------------------------------
__global__ __launch_bounds__(256, 4) void attn_kernel(
    const ushort* __restrict__ qkv, const ushort* __restrict__ vtp,
    ushort* __restrict__ attn_out) {
  const int S = 2048;
  const int bh = blockIdx.x, qblk = blockIdx.y;
  const int h = bh & 15, b = bh >> 4;
  const int t = threadIdx.x, wave = t >> 6, lane = t & 63;
  const int c32 = lane & 31, hi = lane >> 5;
  __shared__ __align__(16) ushort sK[8192];       // 16 KB
  __shared__ __align__(16) ushort sV[8192];       // 16 KB
  const int q0 = qblk * 128;
  const size_t qrow = (size_t)(b * S + q0 + wave * 32 + c32);
  const int swv0 = (c32 ^ (c32 >> 3)) & 15;             // sV swizzle, d=c32
  const int dv1 = 32 + c32;
  const int swv1 = (dv1 ^ (dv1 >> 3)) & 15;             // sV swizzle, d=32+c32
  // Q B-frags: Q[q=lane&31][d = dk*16 + hi*8 + j]  (already scaled by log2e/8)
  bf16x8 qf[4];
  {
    const ushort* qp = qkv + qrow * 2048 + h * 64 + hi * 8;
#pragma unroll
    for (int dk = 0; dk < 4; ++dk) qf[dk] = *(const bf16x8*)(qp + dk * 16);
  }
  f32x16 o0 = {}, o1 = {};
  float li = 0.f;
  const int j0 = wave * 4;

  for (int kv0 = 0; kv0 < S; kv0 += 128) {
    __syncthreads();
#pragma unroll
    for (int c = 0; c < 4; ++c) {
      const int j = j0 + c;
      // sK: slot = dslot*128 + key
      const int dslot = j >> 1, key = (j & 1) * 64 + lane;
      glds16(qkv + (size_t)(b * S + kv0 + key) * 2048 + 1024 + h * 64 + dslot * 8,
             sK + j * 512);
      // sV: lds slot = d*16+ks'; global ks = ks' ^ swz(d)  (keys pi-ordered)
      const int d = j * 4 + (lane >> 4);
      const int ksv = (lane & 15) ^ ((d ^ (d >> 3)) & 15);
      glds16(vtp + (size_t)((b * 16 + h) * 64 + d) * S + kv0 + ksv * 8,
             sV + j * 512);
    }
    __syncthreads();
#pragma unroll
    for (int kt = 0; kt < 4; ++kt) {
      // S^T tile (32 keys x 32 q)
      f32x16 z = {};
#pragma unroll
      for (int dk = 0; dk < 4; ++dk) {
        bf16x8 kf = *(const bf16x8*)(sK + ((dk * 2 + hi) * 128 + kt * 32 + c32) * 8);
        z = __builtin_amdgcn_mfma_f32_32x32x16_bf16(kf, qf[dk], z, 0, 0, 0);
      }
      // p = exp2(z); accumulate li; pack runs to bf16 (w[g]: keys 8g+4hi+..)
      uint2 w[4];
#pragma unroll
      for (int g = 0; g < 4; ++g) {
        const float p0 = EXP2(z[g * 4 + 0]);
        const float p1 = EXP2(z[g * 4 + 1]);
        const float p2 = EXP2(z[g * 4 + 2]);
        const float p3 = EXP2(z[g * 4 + 3]);
        li += (p0 + p1) + (p2 + p3);
        w[g].x = __builtin_amdgcn_perm(__float_as_uint(p1), __float_as_uint(p0),
                                       0x07060302u);
        w[g].y = __builtin_amdgcn_perm(__float_as_uint(p3), __float_as_uint(p2),
                                       0x07060302u);
      }
      // PV: chunk c in {0,1}; B-frag = (w[2c], w[2c+1]) directly (pi order)
#pragma unroll
      for (int c = 0; c < 2; ++c) {
        const uint4 fr = make_uint4(w[2 * c].x, w[2 * c].y,
                                    w[2 * c + 1].x, w[2 * c + 1].y);
        bf16x8 pf;
        __builtin_memcpy(&pf, &fr, 16);
        const int ksl = kt * 4 + c * 2 + hi;   // 8-key slot within 128
        bf16x8 vf0 = *(const bf16x8*)(sV + (c32 * 16 + (ksl ^ swv0)) * 8);
        o0 = __builtin_amdgcn_mfma_f32_32x32x16_bf16(vf0, pf, o0, 0, 0, 0);
        bf16x8 vf1 = *(const bf16x8*)(sV + (dv1 * 16 + (ksl ^ swv1)) * 8);
        o1 = __builtin_amdgcn_mfma_f32_32x32x16_bf16(vf1, pf, o1, 0, 0, 0);
      }
    }
  }
  // join li across lane halves (each half saw half the keys)
  li += __shfl_xor(li, 32);
  const float inv = 1.f / li;
  ushort* orow = attn_out + qrow * 1024 + h * 64;
#pragma unroll
  for (int dt = 0; dt < 2; ++dt) {
    const f32x16 ov = dt ? o1 : o0;
#pragma unroll
    for (int g = 0; g < 4; ++g) {
      float v0 = ov[g * 4 + 0] * inv, v1 = ov[g * 4 + 1] * inv;
      float v2 = ov[g * 4 + 2] * inv, v3 = ov[g * 4 + 3] * inv;
      uint2 w2;
      w2.x = (unsigned)f2bf(v0) | ((unsigned)f2bf(v1) << 16);
      w2.y = (unsigned)f2bf(v2) | ((unsigned)f2bf(v3) << 16);
      *(uint2*)(orow + dt * 32 + g * 8 + hi * 4) = w2;
    }
  }
}

// ---------------------------------------------------------------------------
// LayerNorm over D=1024 per row; input y in bf16, output fp32.
// ---------------------------------------------------------------------------
__global__ __launch_bounds__(256) void ln_kernel(const ushort* __restrict__ yb,
                                                 const float* __restrict__ g,
                                                 const float* __restrict__ bta,
                                                 float* __restrict__ out) {
  const int m = blockIdx.x;
  const int t = threadIdx.x;
  const ushort4 u = ((const ushort4*)(yb + (size_t)m * 1024))[t];
  float4 v;
  v.x = bf2f(u.x); v.y = bf2f(u.y); v.z = bf2f(u.z); v.w = bf2f(u.w);
  float s = v.x + v.y + v.z + v.w;
  float s2 = v.x * v.x + v.y * v.y + v.z * v.z + v.w * v.w;
#pragma unroll
  for (int off = 1; off < 64; off <<= 1) {
    s += __shfl_xor(s, off, 64);
    s2 += __shfl_xor(s2, off, 64);
  }
  __shared__ float red[8];
  const int wave = t >> 6, lane = t & 63;
  if (lane == 0) { red[wave] = s; red[4 + wave] = s2; }
  __syncthreads();
  s = red[0] + red[1] + red[2] + red[3];
  s2 = red[4] + red[5] + red[6] + red[7];
  const float mu = s * (1.f / 1024.f);
  const float var = s2 * (1.f / 1024.f) - mu * mu;
  const float rs = rsqrtf(var + 1e-5f);
  float4 gg = ((const float4*)g)[t];
  float4 bb = ((const float4*)bta)[t];
  float4 o;
  o.x = (v.x - mu) * rs * gg.x + bb.x;
  o.y = (v.y - mu) * rs * gg.y + bb.y;
  o.z = (v.z - mu) * rs * gg.z + bb.z;
  o.w = (v.w - mu) * rs * gg.w + bb.w;
  ((float4*)(out + (size_t)m * 1024))[t] = o;
}

// ---------------------------------------------------------------------------
// Workspace (109 MB):
//  [0,17M)    embb bf16 [4][2049][1024]   (dead after gemm_chunk)
//  [17,49M)   qkvb bf16 [8192][2048] (q,k); yb bf16 alias [17,33M)
//             (qkvb dead after attn)
//  [49,65M)   chunkb bf16
//  [65,81M)   vtb bf16 [B][H][64][S] (pi key order)
//  [81,97M)   attnb bf16 [8192][1024]
//  [97,101M)  cwb  [101,107M) ipwb  [107,109M) opwb
// ---------------------------------------------------------------------------
extern "C" void kernel_launch(void* const* d_in, const int* in_sizes, int n_in,
                              void* d_out, int out_size, void* d_ws, size_t ws_size,
                              hipStream_t stream) {
  const float* emb        = (const float*)d_in[0];
  const float* chunk_w    = (const float*)d_in[1];
  const float* chunk_b    = (const float*)d_in[2];
  const float* in_proj_w  = (const float*)d_in[3];
  const float* in_proj_b  = (const float*)d_in[4];
  const float* out_proj_w = (const float*)d_in[5];
  const float* out_proj_b = (const float*)d_in[6];
  const float* ln_g       = (const float*)d_in[7];
  const float* ln_b       = (const float*)d_in[8];

  char* w = (char*)d_ws;
  const size_t MBy = (size_t)1 << 20;
  ushort* embb   = (ushort*)(w + 0);
  ushort* qkvb   = (ushort*)(w + 17 * MBy);
  ushort* yb     = (ushort*)(w + 17 * MBy);    // alias: live after attn
  ushort* chunkb = (ushort*)(w + 49 * MBy);
  ushort* vtb    = (ushort*)(w + 65 * MBy);
  ushort* attnb  = (ushort*)(w + 81 * MBy);
  ushort* cwb    = (ushort*)(w + 97 * MBy);
  ushort* ipwb   = (ushort*)(w + 101 * MBy);
  ushort* opwb   = (ushort*)(w + 107 * MBy);

  // Phase 1: all conversions in one launch
  cvt_all<<<14340, 256, 0, stream>>>(emb, chunk_w, in_proj_w, out_proj_w,
                                     embb, cwb, ipwb, opwb);

  // Phase 2: chunk = emb[s] W1^T + emb[s+1] W2^T + b  (K=1024 x 2 terms)
  gemm_chunk<<<dim3(8192 / 128, 1024 / 64), 256, 0, stream>>>(
      embb, cwb, chunk_b, chunkb);

  // Phase 3: qkv; Q pre-scaled, K plain -> qkvb[8192][2048]; V^T -> vtb (pi)
  gemm_bt<128><<<dim3(8192 / 128, 3072 / 128), 256, 0, stream>>>(
      chunkb, ipwb, in_proj_b, 8192, 3072, 1024, 1, qkvb, nullptr, vtb);

  // Phase 4: attention (x = b*16+h for XCD-local K/V; q-tile 128)
  attn_kernel<<<dim3(64, 2048 / 128, 1), 256, 0, stream>>>(qkvb, vtb, attnb);

  // Phase 5: y = bf16(attn @ out_proj_w^T + b + chunk)  (N=1024 K=1024)
  gemm_bt<64><<<dim3(8192 / 128, 1024 / 64), 256, 0, stream>>>(
      attnb, opwb, out_proj_b, 8192, 1024, 1024, 2, yb, chunkb, nullptr);

  // Phase 6: LayerNorm (bf16 in, fp32 out) -> d_out
  ln_kernel<<<8192, 256, 0, stream>>>(yb, ln_g, ln_b, (float*)d_out);
}